// Round 6
// baseline (207.267 us; speedup 1.0000x reference)
//
#include <hip/hip_runtime.h>
#include <hip/hip_fp16.h>

__device__ __forceinline__ float2 h2f2(unsigned int u) {
  return __half22float2(__builtin_bit_cast(__half2, u));
}
__device__ __forceinline__ unsigned int f2h2(float a, float b) {
  return __builtin_bit_cast(unsigned int, __floats2half2_rn(a, b));
}

#if __has_builtin(__builtin_amdgcn_fdot2)
typedef _Float16 h2v __attribute__((ext_vector_type(2)));
__device__ __forceinline__ float fdot2(unsigned int a, unsigned int b, float c) {
  return __builtin_amdgcn_fdot2(__builtin_bit_cast(h2v, a),
                                __builtin_bit_cast(h2v, b), c, false);
}
#else
__device__ __forceinline__ float fdot2(unsigned int a, unsigned int b, float c) {
  float2 fa = h2f2(a), fb = h2f2(b);
  return fmaf(fa.y, fb.y, fmaf(fa.x, fb.x, c));
}
#endif

// ---------------- K0: LayerNorm stats per (bb, pixel-pair) ----------------
__global__ __launch_bounds__(256) void k_stats(const float2* __restrict__ x2,
                                               float4* __restrict__ stats4) {
  int id = blockIdx.x * 256 + threadIdx.x;   // 32 * 8192
  int bb = id >> 13;
  int jp = id & 8191;
  const float2* xp = x2 + ((size_t)bb << 19) + jp;
  float s0 = 0.f, q0 = 0.f, s1 = 0.f, q1 = 0.f;
#pragma unroll
  for (int ci = 0; ci < 64; ++ci) {
    float2 v = xp[(size_t)ci << 13];
    s0 += v.x; q0 = fmaf(v.x, v.x, q0);
    s1 += v.y; q1 = fmaf(v.y, v.y, q1);
  }
  float mu0 = s0 * (1.f / 64.f), mu1 = s1 * (1.f / 64.f);
  float4 r;
  r.x = mu0; r.y = rsqrtf(fmaf(-mu0, mu0, q0 * (1.f / 64.f)) + 1e-5f);
  r.z = mu1; r.w = rsqrtf(fmaf(-mu1, mu1, q1 * (1.f / 64.f)) + 1e-5f);
  stats4[id] = r;
}

// ---------------- K0b: pack all weights to half2 ----------------
__global__ __launch_bounds__(256) void k_wpack(
    const float* __restrict__ qkvw, const float* __restrict__ dww,
    const float* __restrict__ projw, unsigned int* __restrict__ qkvpk,
    unsigned int* __restrict__ dwpk, unsigned int* __restrict__ projpk) {
  int t = blockIdx.x * 256 + threadIdx.x;
  if (t < 2048) {
    int o = t >> 5, c2 = t & 31;
    projpk[t] = f2h2(projw[(o << 6) + 2 * c2], projw[(o << 6) + 2 * c2 + 1]);
  } else if (t < 2432) {
    int i = t - 2048;
    int ch = i >> 3, tp = i & 7;
    qkvpk[i] = f2h2(qkvw[(ch << 4) + 2 * tp], qkvw[(ch << 4) + 2 * tp + 1]);
  } else if (t < 2648) {
    int i = t - 2432;
    int pl = i / 9, k = i - pl * 9;
    dwpk[i] = f2h2(dww[18 * pl + k], dww[18 * pl + 9 + k]);
  }
}

// ---------------- K1: fused LN + 1x1 + dw3x3 + attn partials + v ----------
// grid (32 tiles of 32x16, 128 = bt*64+ci), block 256.
// 3 chunks of 8 planes: m=0 -> heads 0,1; m=1 -> heads 2,3; then v (16 ch).
__global__ __launch_bounds__(256) void k_fused(
    const float* __restrict__ x, const float2* __restrict__ stats2,
    const float* __restrict__ lnw, const float* __restrict__ lnb,
    const unsigned int* __restrict__ qkvpk, const unsigned int* __restrict__ dwpk,
    unsigned int* __restrict__ vbuf, float* __restrict__ Sacc,
    float* __restrict__ Nacc) {
  __shared__ unsigned int pre[5040];   // 8 planes x [18][35]; alias qk[16][272]
  int tid = threadIdx.x;
  int bc = blockIdx.y, bt = bc >> 6, ci = bc & 63;
  int tx0 = (blockIdx.x & 3) << 5, ty0 = (blockIdx.x >> 2) << 4;
  float lw = lnw[ci], lb = lnb[ci];

  // ---- stage LN'd x as (t,t+1) half2 in registers; pos = tid + 256*it
  unsigned int wc[3][8];
  int waddr[3];
  {
    size_t xci = ((size_t)(bt * 1024 + ci)) << 14;
    int sbase = bt << 18;
#pragma unroll
    for (int it = 0; it < 3; ++it) {
      int pos = tid + (it << 8);
      bool act = pos < 612;
      int hy = pos / 34, hx = pos - hy * 34;
      int gy = ty0 + hy - 1, gx = tx0 + hx - 1;
      bool ok = act && ((unsigned)gy < 128u) && ((unsigned)gx < 128u);
      waddr[it] = act ? (hy * 35 + hx) : -1;
      int gp = (gy << 7) + gx;
#pragma unroll
      for (int tp = 0; tp < 8; ++tp) {
        unsigned int w = 0;
        if (ok) {
          float x0 = x[xci + ((size_t)(2 * tp) << 20) + gp];
          float x1 = x[xci + ((size_t)(2 * tp + 1) << 20) + gp];
          float2 s0 = stats2[sbase + (2 * tp) * 16384 + gp];
          float2 s1 = stats2[sbase + (2 * tp + 1) * 16384 + gp];
          w = f2h2(fmaf((x0 - s0.x) * s0.y, lw, lb),
                   fmaf((x1 - s1.x) * s1.y, lw, lb));
        }
        wc[it][tp] = w;
      }
    }
  }

  int iy = tid >> 4, jx = tid & 15;
  int dwbase = iy * 35 + 2 * jx;

  // ---- head-pair chunks
  for (int m = 0; m < 2; ++m) {
    // 1x1 (f32 accum via dot2), pack per plane immediately (2 live accs)
#pragma unroll
    for (int it = 0; it < 3; ++it) {
      if (waddr[it] >= 0) {
#pragma unroll
        for (int pl = 0; pl < 8; ++pl) {
          int cE = 2 * pl;
          int gchE = (cE < 8) ? (8 * m + cE) : (16 + 8 * m + (cE - 8));
          float sE = 0.f, sO = 0.f;
#pragma unroll
          for (int tp = 0; tp < 8; ++tp) {
            sE = fdot2(wc[it][tp], qkvpk[gchE * 8 + tp], sE);
            sO = fdot2(wc[it][tp], qkvpk[(gchE + 1) * 8 + tp], sO);
          }
          pre[pl * 630 + waddr[it]] = f2h2(sE, sO);
        }
      }
    }
    __syncthreads();
    // dw 3x3 (packed fp16)
    unsigned int qkw[16];
#pragma unroll
    for (int pl = 0; pl < 8; ++pl) {
      int gpl = (pl < 4) ? (4 * m + pl) : (8 + 4 * m + (pl - 4));
      const unsigned int* wp = dwpk + gpl * 9;
      __half2 a0 = __floats2half2_rn(0.f, 0.f), a1 = a0;
      int base = pl * 630 + dwbase;
#pragma unroll
      for (int dy = 0; dy < 3; ++dy) {
        __half2 d0 = __builtin_bit_cast(__half2, pre[base + dy * 35 + 0]);
        __half2 d1 = __builtin_bit_cast(__half2, pre[base + dy * 35 + 1]);
        __half2 d2 = __builtin_bit_cast(__half2, pre[base + dy * 35 + 2]);
        __half2 d3 = __builtin_bit_cast(__half2, pre[base + dy * 35 + 3]);
        __half2 w0 = __builtin_bit_cast(__half2, wp[dy * 3 + 0]);
        __half2 w1 = __builtin_bit_cast(__half2, wp[dy * 3 + 1]);
        __half2 w2 = __builtin_bit_cast(__half2, wp[dy * 3 + 2]);
        a0 = __hfma2(w0, d0, a0); a0 = __hfma2(w1, d1, a0); a0 = __hfma2(w2, d2, a0);
        a1 = __hfma2(w0, d1, a1); a1 = __hfma2(w1, d2, a1); a1 = __hfma2(w2, d3, a1);
      }
      unsigned int u0 = __builtin_bit_cast(unsigned int, a0);
      unsigned int u1 = __builtin_bit_cast(unsigned int, a1);
      qkw[2 * pl]     = (u0 & 0xFFFFu) | (u1 << 16);      // chEven: (px0,px1)
      qkw[2 * pl + 1] = (u0 >> 16) | (u1 & 0xFFFF0000u);  // chOdd
    }
    __syncthreads();   // pre reads done; safe to alias
#pragma unroll
    for (int r = 0; r < 16; ++r) pre[r * 272 + tid] = qkw[r];
    __syncthreads();
    {  // S partials: 2 heads x 16 combos x 8 px-chunks
      int combo = tid >> 3, pc = tid & 7;
      int hp = combo >> 4, cd = combo & 15, cc = cd >> 2, dd = cd & 3;
      const unsigned int* qrow = pre + (4 * hp + cc) * 272;
      const unsigned int* krow = pre + (8 + 4 * hp + dd) * 272;
      float s = 0.f;
#pragma unroll
      for (int i = 0; i < 32; ++i)
        s = fdot2(qrow[pc + (i << 3)], krow[pc + (i << 3)], s);
      s += __shfl_xor(s, 1); s += __shfl_xor(s, 2); s += __shfl_xor(s, 4);
      if (pc == 0)
        atomicAdd(&Sacc[((bc << 2) + 2 * m + hp) * 16 + cc * 4 + dd], s);
    }
    {  // N partials: 16 rows x 16 px-chunks
      int row = tid >> 4, pc = tid & 15;
      const unsigned int* rp = pre + row * 272;
      float n = 0.f;
#pragma unroll
      for (int i = 0; i < 16; ++i) {
        unsigned int v = rp[pc + (i << 4)];
        n = fdot2(v, v, n);
      }
      n += __shfl_xor(n, 1); n += __shfl_xor(n, 2);
      n += __shfl_xor(n, 4); n += __shfl_xor(n, 8);
      if (pc == 0) {
        int g = (row < 8) ? (8 * m + row) : (16 + 8 * m + (row - 8));
        atomicAdd(&Nacc[(bc << 5) + g], n);
      }
    }
    __syncthreads();   // qk reads done before next chunk's 1x1 writes
  }

  // ---- v chunk: planes 16..23 (v channels 0..15)
#pragma unroll
  for (int it = 0; it < 3; ++it) {
    if (waddr[it] >= 0) {
#pragma unroll
      for (int pl = 0; pl < 8; ++pl) {
        int gchE = 32 + 2 * pl;
        float sE = 0.f, sO = 0.f;
#pragma unroll
        for (int tp = 0; tp < 8; ++tp) {
          sE = fdot2(wc[it][tp], qkvpk[gchE * 8 + tp], sE);
          sO = fdot2(wc[it][tp], qkvpk[(gchE + 1) * 8 + tp], sO);
        }
        pre[pl * 630 + waddr[it]] = f2h2(sE, sO);
      }
    }
  }
  __syncthreads();
#pragma unroll
  for (int pl = 0; pl < 8; ++pl) {
    const unsigned int* wp = dwpk + (16 + pl) * 9;
    __half2 a0 = __floats2half2_rn(0.f, 0.f), a1 = a0;
    int base = pl * 630 + dwbase;
#pragma unroll
    for (int dy = 0; dy < 3; ++dy) {
      __half2 d0 = __builtin_bit_cast(__half2, pre[base + dy * 35 + 0]);
      __half2 d1 = __builtin_bit_cast(__half2, pre[base + dy * 35 + 1]);
      __half2 d2 = __builtin_bit_cast(__half2, pre[base + dy * 35 + 2]);
      __half2 d3 = __builtin_bit_cast(__half2, pre[base + dy * 35 + 3]);
      __half2 w0 = __builtin_bit_cast(__half2, wp[dy * 3 + 0]);
      __half2 w1 = __builtin_bit_cast(__half2, wp[dy * 3 + 1]);
      __half2 w2 = __builtin_bit_cast(__half2, wp[dy * 3 + 2]);
      a0 = __hfma2(w0, d0, a0); a0 = __hfma2(w1, d1, a0); a0 = __hfma2(w2, d2, a0);
      a1 = __hfma2(w0, d1, a1); a1 = __hfma2(w1, d2, a1); a1 = __hfma2(w2, d3, a1);
    }
    uint2 st2;
    st2.x = __builtin_bit_cast(unsigned int, a0);   // (chE,chO)@px0
    st2.y = __builtin_bit_cast(unsigned int, a1);   // @px1
    size_t idx = ((size_t)(bc * 8 + pl) << 14) +
                 (size_t)((ty0 + iy) << 7) + tx0 + 2 * jx;
    *reinterpret_cast<uint2*>(vbuf + idx) = st2;
  }
}

// ---------------- K2: softmax -> packed fp16 attention rows ----------------
__global__ __launch_bounds__(256) void k_softmax(
    const float* __restrict__ Sacc, const float* __restrict__ Nacc,
    const float* __restrict__ temp, unsigned int* __restrict__ attnpk) {
  int idx = blockIdx.x * 256 + threadIdx.x;
  if (idx >= 512) return;
  int b = idx >> 2, hd = idx & 3;   // b = bt*64 + ci
  int bt = b >> 6, ci = b & 63;
  float tp = temp[hd];
  float iq[4], ik[4];
#pragma unroll
  for (int c = 0; c < 4; ++c) {
    iq[c] = 1.f / fmaxf(sqrtf(Nacc[(b << 5) + (hd << 2) + c]), 1e-12f);
    ik[c] = 1.f / fmaxf(sqrtf(Nacc[(b << 5) + 16 + (hd << 2) + c]), 1e-12f);
  }
  const float* Sp = Sacc + ((b << 2) + hd) * 16;
#pragma unroll
  for (int c = 0; c < 4; ++c) {
    float l[4];
#pragma unroll
    for (int d = 0; d < 4; ++d) l[d] = Sp[c * 4 + d] * iq[c] * ik[d] * tp;
    float m = fmaxf(fmaxf(l[0], l[1]), fmaxf(l[2], l[3]));
    float e0 = expf(l[0] - m), e1 = expf(l[1] - m);
    float e2 = expf(l[2] - m), e3 = expf(l[3] - m);
    float inv = 1.f / (e0 + e1 + e2 + e3);
    unsigned int* dst = attnpk + ((((bt * 4 + hd) * 4 + c) << 7) + ci * 2);
    dst[0] = f2h2(e0 * inv, e1 * inv);
    dst[1] = f2h2(e2 * inv, e3 * inv);
  }
}

// ---------------- K3: out = proj @ (attn . v), 2 px/thread ----------------
// grid (32, 32 = bt*16 + hd*4 + c), block 256.
__global__ __launch_bounds__(256) void k_outproj(
    const unsigned int* __restrict__ vbuf, const unsigned int* __restrict__ attnpk,
    const unsigned int* __restrict__ projpk, float* __restrict__ out) {
  int comb = blockIdx.y;
  int bt = comb >> 4, hd = (comb >> 2) & 3, c = comb & 3;
  int px = ((blockIdx.x << 8) + threadIdx.x) << 1;

  const unsigned int* apk = attnpk + (((bt * 4 + hd) * 4 + c) << 7);  // uniform
  float accA[64], accB[64];
#pragma unroll
  for (int o = 0; o < 64; ++o) { accA[o] = 0.f; accB[o] = 0.f; }

  size_t vbase = ((((size_t)bt * 512) + hd * 2) << 14) + px;
  for (int ci2 = 0; ci2 < 32; ++ci2) {
    size_t off0 = vbase + (((size_t)(2 * ci2) * 8) << 14);
    size_t off1 = off0 + ((size_t)8 << 14);
    uint2 v0a = *reinterpret_cast<const uint2*>(&vbuf[off0]);
    uint2 v0b = *reinterpret_cast<const uint2*>(&vbuf[off0 + (1 << 14)]);
    uint2 v1a = *reinterpret_cast<const uint2*>(&vbuf[off1]);
    uint2 v1b = *reinterpret_cast<const uint2*>(&vbuf[off1 + (1 << 14)]);
    float y0A = fdot2(v0a.x, apk[4 * ci2 + 0], fdot2(v0b.x, apk[4 * ci2 + 1], 0.f));
    float y0B = fdot2(v0a.y, apk[4 * ci2 + 0], fdot2(v0b.y, apk[4 * ci2 + 1], 0.f));
    float y1A = fdot2(v1a.x, apk[4 * ci2 + 2], fdot2(v1b.x, apk[4 * ci2 + 3], 0.f));
    float y1B = fdot2(v1a.y, apk[4 * ci2 + 2], fdot2(v1b.y, apk[4 * ci2 + 3], 0.f));
    unsigned int y2A = f2h2(y0A, y1A);
    unsigned int y2B = f2h2(y0B, y1B);
#pragma unroll
    for (int o = 0; o < 64; ++o) {
      unsigned int w = projpk[(o << 5) + ci2];
      accA[o] = fdot2(y2A, w, accA[o]);
      accB[o] = fdot2(y2B, w, accB[o]);
    }
  }
  float* op = out + (((size_t)comb << 6) << 14) + px;
#pragma unroll
  for (int o = 0; o < 64; ++o)
    *reinterpret_cast<float2*>(&op[(size_t)o << 14]) = make_float2(accA[o], accB[o]);
}

extern "C" void kernel_launch(void* const* d_in, const int* in_sizes, int n_in,
                              void* d_out, int out_size, void* d_ws, size_t ws_size,
                              hipStream_t stream) {
  const float* x = (const float*)d_in[0];
  const float* lnw = (const float*)d_in[1];
  const float* lnb = (const float*)d_in[2];
  const float* qkvw = (const float*)d_in[3];
  const float* dww = (const float*)d_in[4];
  const float* projw = (const float*)d_in[5];
  const float* temp = (const float*)d_in[6];
  float* out = (float*)d_out;

  // workspace: vbuf 64 MiB | stats 4 MiB | Sacc | Nacc | attnpk | projpk |
  //            qkvpk | dwpk  (~68.1 MiB total)
  unsigned int* vbuf = (unsigned int*)d_ws;
  char* tail = (char*)d_ws + 67108864ull;
  float4* stats4 = (float4*)tail;                         // 4 MiB
  float* Sacc = (float*)(tail + 4194304ull);              // 8192 f32
  float* Nacc = Sacc + 8192;                              // 4096 f32
  unsigned int* attnpk = (unsigned int*)(Nacc + 4096);    // 4096 u32
  unsigned int* projpk = attnpk + 4096;                   // 2048 u32
  unsigned int* qkvpk = projpk + 2048;                    // 384 u32
  unsigned int* dwpk = qkvpk + 384;                       // 216 u32

  hipMemsetAsync(Sacc, 0, (8192 + 4096) * sizeof(float), stream);
  k_stats<<<dim3(1024), dim3(256), 0, stream>>>((const float2*)x, stats4);
  k_wpack<<<dim3(11), dim3(256), 0, stream>>>(qkvw, dww, projw, qkvpk, dwpk, projpk);
  k_fused<<<dim3(32, 128), dim3(256), 0, stream>>>(
      x, (const float2*)stats4, lnw, lnb, qkvpk, dwpk, vbuf, Sacc, Nacc);
  k_softmax<<<dim3(2), dim3(256), 0, stream>>>(Sacc, Nacc, temp, attnpk);
  k_outproj<<<dim3(32, 32), dim3(256), 0, stream>>>(vbuf, attnpk, projpk, out);
}